// Round 11
// baseline (119.411 us; speedup 1.0000x reference)
//
#include <hip/hip_runtime.h>
#include <hip/hip_bf16.h>

// Problem dims (fixed by the reference setup_inputs)
#define BB 8
#define TT 4096
#define SS 256
#define DD 512

typedef __attribute__((ext_vector_type(8))) short short8;
typedef __attribute__((ext_vector_type(4))) float floatx4;
typedef __attribute__((ext_vector_type(4))) int intx4;

// Packed RNE f32x2 -> bf16x2 (v_cvt_pk_bf16_f32 on gfx950).
__device__ inline int pk2(float a, float b) {
  __hip_bfloat162 h = __float22bfloat162_rn(make_float2(a, b));
  int r;
  __builtin_memcpy(&r, &h, 4);
  return r;
}

// Pack 8 consecutive-k f32 values into a bf16 MFMA fragment.
__device__ inline short8 cvt8(float4 f0, float4 f1) {
  intx4 p;
  p[0] = pk2(f0.x, f0.y);
  p[1] = pk2(f0.z, f0.w);
  p[2] = pk2(f1.x, f1.y);
  p[3] = pk2(f1.z, f1.w);
  return __builtin_bit_cast(short8, p);
}

// K1: pack spk (8,256,512) f32 -> bf16 in global_load_lds DMA order.
// Region (b, kh): 256 cols x 128 k as 4096 16B-units; unit u:
// col = u>>4, stored slot = u&15 holding logical k-block (u&15)^(col&15)
// [XOR-16 swizzle baked in; 256-B rows = measured-conflict-free pattern].
// 32 regions x 64 KB = 2 MB in ws.
__global__ __launch_bounds__(256) void cos_packB_kernel(
    const float* __restrict__ spk, short* __restrict__ bp) {
  const int idx = blockIdx.x;  // 32 regions
  const int b = idx >> 2;      // 0..7
  const int kh = idx & 3;      // 0..3 (k-quarter of 128)
  const int tid = threadIdx.x;
  short* dst = bp + (size_t)idx * 4096 * 8;
#pragma unroll
  for (int j = 0; j < 16; j++) {
    int u = j * 256 + tid;
    int col = u >> 4;
    int kblk = (u & 15) ^ (col & 15);
    const float* src =
        spk + ((size_t)(b * SS + col)) * DD + kh * 128 + kblk * 8;
    float4 f0 = *(const float4*)src;
    float4 f1 = *(const float4*)(src + 4);
    short8 o = cvt8(f0, f1);
    *(short8*)(dst + (size_t)u * 8) = o;
  }
}

// K2: fused cosine scorer,
//   C[b] = diag(1/||x||) * (bf16(X[b]) * bf16(Y[b])^T) * diag(1/||y||)
// Tile 128 M x 256 N (FULL N per block -> A staged exactly once device-wide;
// staged-VMEM bytes 225 -> 161 MB, the r8/r10-validated governing model).
// Grid 256 blocks = 1/CU. LDS: sA 32 KB (f32, BK=64, XOR-16 swizzle,
// r6-proven conflict-free) + sB 64 KB (pre-packed bf16 region: 256 cols x
// 128 k, staged every other kt via contiguous per-lane DMA). B-frag = one
// ds_read_b128, no cvt. Per-row/col sumsq via gram MFMAs (diag of
// mfma(f,f) = row sumsq): waves (0,0),(1,1) -> A-rows; (0,1),(1,0) -> B-cols.
__global__ __launch_bounds__(256) void cos_fused_kernel(
    const float* __restrict__ xs, const short* __restrict__ bp,
    float* __restrict__ out) {
  __shared__ float sA[128 * 64];    // 32 KB: A tile, 64 k (f32)
  __shared__ short sB[256 * 128];   // 64 KB: B tile, 128 k (bf16, packed)
  __shared__ float scX[128];
  __shared__ float scY[256];

  const int tid = threadIdx.x;
  const int wave = tid >> 6;
  const int lane = tid & 63;
  const int tm = blockIdx.x;  // 0..31
  const int b = blockIdx.y;   // 0..7

  const float* Abase = xs + ((size_t)b * TT + tm * 128) * DD;
  const short* Bregions = bp + (size_t)(b * 4) * 4096 * 8;

  floatx4 acc[4][8];
#pragma unroll
  for (int i = 0; i < 4; i++)
#pragma unroll
    for (int j = 0; j < 8; j++) acc[i][j] = (floatx4){0.f, 0.f, 0.f, 0.f};
  floatx4 accG[8];  // gram accumulators (4 used by A-waves, 8 by B-waves)
#pragma unroll
  for (int i = 0; i < 8; i++) accG[i] = (floatx4){0.f, 0.f, 0.f, 0.f};

  const int wm = wave >> 1;   // rows wm*64 .. +64
  const int wn = wave & 1;    // cols wn*128 .. +128
  const int quad = lane >> 4;
  const int l15 = lane & 15;
  const bool gramA = (wm == wn);

  // A staging map: 16B unit s = j*256 + tid; row = s>>4 (16 units/row);
  // slot = s&15 holds logical block (slot ^ (row&15)).
  int aoff[8];
#pragma unroll
  for (int j = 0; j < 8; j++) {
    int s = j * 256 + tid;
    int row = s >> 4;
    int blk = (s & 15) ^ (row & 15);
    aoff[j] = row * DD + blk * 4;
  }

  for (int kt = 0; kt < DD / 64; ++kt) {
    // B DMA: 64 KB pre-packed bf16 region (covers k for kt, kt+1).
    if ((kt & 1) == 0) {
      const short* gB = Bregions + (size_t)(kt >> 1) * 4096 * 8;
#pragma unroll
      for (int j = 0; j < 16; j++) {
        // Per-lane source: unit u = j*256 + wave*64 + lane (16 B each).
        __builtin_amdgcn_global_load_lds(
            (const __attribute__((address_space(1))) unsigned int*)(gB +
                (size_t)(j * 256 + wave * 64 + lane) * 8),
            (__attribute__((address_space(3))) unsigned int*)(sB +
                (size_t)(j * 256 + wave * 64) * 8),
            16, 0, 0);
      }
    }
    // A DMA for this kt.
#pragma unroll
    for (int j = 0; j < 8; j++) {
      __builtin_amdgcn_global_load_lds(
          (const __attribute__((address_space(1))) unsigned int*)(Abase +
              aoff[j] + kt * 64),
          (__attribute__((address_space(3))) unsigned int*)(sA +
              (j * 256 + wave * 64) * 4),
          16, 0, 0);
    }
    __syncthreads();

#pragma unroll
    for (int ks = 0; ks < 2; ks++) {
      short8 af[4], bfr[8];
      const int b0s = ks * 8 + quad * 2;  // A frag: first 16B f32 block
      const int bslot = (kt & 1) * 8 + ks * 4 + quad;  // B frag: bf16 slot
#pragma unroll
      for (int im = 0; im < 4; im++) {
        int row = wm * 64 + im * 16 + l15;
        int s0 = b0s ^ (row & 15);
        int s1 = (b0s + 1) ^ (row & 15);
        float4 f0 = *(const float4*)(sA + row * 64 + s0 * 4);
        float4 f1 = *(const float4*)(sA + row * 64 + s1 * 4);
        af[im] = cvt8(f0, f1);
      }
#pragma unroll
      for (int in = 0; in < 8; in++) {
        int col = wn * 128 + in * 16 + l15;
        int s = bslot ^ (col & 15);
        bfr[in] = *(const short8*)(sB + col * 128 + s * 8);
      }
#pragma unroll
      for (int im = 0; im < 4; im++)
#pragma unroll
        for (int in = 0; in < 8; in++)
          acc[im][in] = __builtin_amdgcn_mfma_f32_16x16x32_bf16(
              af[im], bfr[in], acc[im][in], 0, 0, 0);
      if (gramA) {
#pragma unroll
        for (int im = 0; im < 4; im++)
          accG[im] = __builtin_amdgcn_mfma_f32_16x16x32_bf16(
              af[im], af[im], accG[im], 0, 0, 0);
      } else {
#pragma unroll
        for (int in = 0; in < 8; in++)
          accG[in] = __builtin_amdgcn_mfma_f32_16x16x32_bf16(
              bfr[in], bfr[in], accG[in], 0, 0, 0);
      }
    }
    __syncthreads();
  }

  // Extract gram diagonals -> inverse norms. C/D layout: col = l15,
  // row = quad*4 + r; diagonal element d: lane with l15==d, quad==d>>2,
  // reg r = d&3.
  if (quad == (l15 >> 2)) {
    if (gramA) {
      // waves (0,0): rows 0..63, (1,1): rows 64..127
#pragma unroll
      for (int i = 0; i < 4; i++)
        scX[wm * 64 + i * 16 + l15] =
            1.0f / fmaxf(sqrtf(accG[i][l15 & 3]), 1e-8f);
    } else {
      // waves (0,1): cols 128..255, (1,0): cols 0..127
#pragma unroll
      for (int i = 0; i < 8; i++)
        scY[wn * 128 + i * 16 + l15] =
            1.0f / fmaxf(sqrtf(accG[i][l15 & 3]), 1e-8f);
    }
  }
  __syncthreads();

  // Epilogue: apply cosine scales (dot * (1/||x||) * (1/||y||)).
  float* Obase = out + ((size_t)b * TT + tm * 128) * SS;
#pragma unroll
  for (int im = 0; im < 4; im++) {
#pragma unroll
    for (int in = 0; in < 8; in++) {
      int col = wn * 128 + in * 16 + l15;
      float yv = scY[col];
#pragma unroll
      for (int r = 0; r < 4; r++) {
        int row = wm * 64 + im * 16 + quad * 4 + r;
        Obase[row * SS + col] = acc[im][in][r] * scX[row] * yv;
      }
    }
  }
}

extern "C" void kernel_launch(void* const* d_in, const int* in_sizes, int n_in,
                              void* d_out, int out_size, void* d_ws,
                              size_t ws_size, hipStream_t stream) {
  const float* xs = (const float*)d_in[0];   // (8,4096,512) f32
  const float* spk = (const float*)d_in[1];  // (8,256,512) f32
  float* out = (float*)d_out;                // (8,4096,256) f32
  short* bp = (short*)d_ws;                  // 2 MB packed bf16 B

  hipLaunchKernelGGL(cos_packB_kernel, dim3(32), dim3(256), 0, stream, spk,
                     bp);
  hipLaunchKernelGGL(cos_fused_kernel, dim3(TT / 128, BB), dim3(256), 0,
                     stream, xs, bp, out);
}